// Round 6
// baseline (251.545 us; speedup 1.0000x reference)
//
#include <hip/hip_runtime.h>
#include <hip/hip_bf16.h>

typedef __bf16 bf16x8 __attribute__((ext_vector_type(8)));
typedef short s16x4 __attribute__((ext_vector_type(4)));
typedef float floatx4 __attribute__((ext_vector_type(4)));
typedef __hip_bfloat16 bf16;

#define T_SEQ 2048
#define NH 16
#define HD 64
#define CDIM 1024

// async global->LDS, 16B/lane. ldsbase MUST be wave-uniform; HW stores lane i at ldsbase+i*16.
__device__ __forceinline__ void gload16(const bf16* g, bf16* ldsbase) {
  __builtin_amdgcn_global_load_lds((const __attribute__((address_space(1))) void*)g,
                                   (__attribute__((address_space(3))) void*)ldsbase, 16, 0, 0);
}

// ---------------- fp32 -> bf16 cast (4 elems/thread) ----------------
__global__ __launch_bounds__(256) void cast_bf16_kernel(const float* __restrict__ in,
                                                        bf16* __restrict__ out) {
  int i = blockIdx.x * 256 + threadIdx.x;
  const float4 v = ((const float4*)in)[i];
  union { bf16 h[4]; uint2 u; } p;
  p.h[0] = __float2bfloat16(v.x);
  p.h[1] = __float2bfloat16(v.y);
  p.h[2] = __float2bfloat16(v.z);
  p.h[3] = __float2bfloat16(v.w);
  ((uint2*)out)[i] = p.u;
}

// ---------------- LDS-tiled transpose + cast: out_bf16[Cc][R] = in_f32[R][Cc] ----------------
__global__ __launch_bounds__(256) void transpose_cast(const float* __restrict__ in,
                                                      bf16* __restrict__ out,
                                                      int R, int Cc) {
  __shared__ float tile[32][33];
  const int bx = blockIdx.x * 32;
  const int by = blockIdx.y * 32;
  const int tx = threadIdx.x & 31, ty = threadIdx.x >> 5;
#pragma unroll
  for (int i = 0; i < 32; i += 8)
    tile[ty + i][tx] = in[(size_t)(by + ty + i) * Cc + bx + tx];
  __syncthreads();
#pragma unroll
  for (int i = 0; i < 32; i += 8)
    out[(size_t)(bx + ty + i) * R + by + tx] = __float2bfloat16(tile[tx][ty + i]);
}

// ---------------- RoPE table ----------------
__global__ void rope_tab_kernel(float2* __restrict__ tab) {
  int idx = blockIdx.x * 256 + threadIdx.x;  // 2048*32
  int t = idx >> 5, j = idx & 31;
  float w = exp2f(-13.287712379549449f * (float)(2 * j + 1) * (1.0f / 64.0f));
  float ang = (float)(t + 1) * w;
  tab[idx] = make_float2(cosf(ang), sinf(ang));
}

// ---------------- 128x128x(BK=32) bf16 MFMA GEMM, B^T input, global_load_lds staging ----
template <int MODE>
__global__ __launch_bounds__(256) void gemm_bt(
    const bf16* __restrict__ A, const bf16* __restrict__ BT, float* __restrict__ CoutF,
    const float2* __restrict__ tab, bf16* __restrict__ Qr, bf16* __restrict__ Kr,
    bf16* __restrict__ Vt, int M, int N, int K) {
  constexpr int LDK = 32;  // unpadded: global_load_lds dest is lane-contiguous
  __shared__ __align__(16) bf16 As[128 * LDK];
  __shared__ __align__(16) bf16 Bs[128 * LDK];
  const int tid = threadIdx.x, lane = tid & 63, wave = tid >> 6;
  const int quad = lane >> 4, c16 = lane & 15;
  const int tile_m = blockIdx.y * 128, tile_n = blockIdx.x * 128;
  const int wm = (wave >> 1) * 64, wn = (wave & 1) * 64;
  const int r0 = tid >> 2, cp4 = tid & 3;
  bf16* ldsA0 = &As[wave * 512];           // wave-uniform bases (HW adds lane*16B)
  bf16* ldsA1 = &As[2048 + wave * 512];
  bf16* ldsB0 = &Bs[wave * 512];
  bf16* ldsB1 = &Bs[2048 + wave * 512];
  floatx4 acc[4][4] = {};
  for (int k0 = 0; k0 < K; k0 += 32) {
    __syncthreads();
    gload16(&A[(size_t)(tile_m + r0) * K + k0 + cp4 * 8], ldsA0);
    gload16(&A[(size_t)(tile_m + r0 + 64) * K + k0 + cp4 * 8], ldsA1);
    gload16(&BT[(size_t)(tile_n + r0) * K + k0 + cp4 * 8], ldsB0);
    gload16(&BT[(size_t)(tile_n + r0 + 64) * K + k0 + cp4 * 8], ldsB1);
    __syncthreads();
    bf16x8 af[4], bfr[4];
#pragma unroll
    for (int i = 0; i < 4; i++)
      af[i] = *(const bf16x8*)&As[(wm + i * 16 + c16) * LDK + quad * 8];
#pragma unroll
    for (int i = 0; i < 4; i++)
      bfr[i] = *(const bf16x8*)&Bs[(wn + i * 16 + c16) * LDK + quad * 8];
#pragma unroll
    for (int mi = 0; mi < 4; mi++)
#pragma unroll
      for (int ni = 0; ni < 4; ni++)
        acc[mi][ni] = __builtin_amdgcn_mfma_f32_16x16x32_bf16(af[mi], bfr[ni], acc[mi][ni], 0, 0, 0);
  }
  // C/D layout (m89): col = lane&15, row = quad*4 + reg
  if (MODE == 0) {
#pragma unroll
    for (int mi = 0; mi < 4; mi++) {
      int row0 = tile_m + wm + mi * 16 + quad * 4;
#pragma unroll
      for (int ni = 0; ni < 4; ni++) {
        int col = tile_n + wn + ni * 16 + c16;
#pragma unroll
        for (int r = 0; r < 4; r++)
          CoutF[(size_t)(row0 + r) * N + col] = acc[mi][ni][r];
      }
    }
  } else {
#pragma unroll
    for (int ni = 0; ni < 4; ni++) {
      int colg = tile_n + wn + ni * 16 + c16;
      int seg = colg >> 10;  // 0=q 1=k 2=v
      int cc = colg & 1023;
      int h = cc >> 6, d = cc & 63, j = d >> 1;
#pragma unroll
      for (int mi = 0; mi < 4; mi++) {
        int row0 = tile_m + wm + mi * 16 + quad * 4;
#pragma unroll
        for (int r = 0; r < 4; r++) {
          int rowg = row0 + r;
          int b = rowg >> 11, t = rowg & 2047;
          float val = acc[mi][ni][r];
          float partner = __shfl_xor(val, 1, 64);
          size_t bh = (size_t)(b * NH + h);
          if (seg == 2) {
            Vt[(bh * HD + d) * T_SEQ + t] = __float2bfloat16(val);
          } else {
            float2 sc = tab[t * 32 + j];
            float outv = ((d & 1) == 0) ? (val * sc.x - partner * sc.y)
                                        : (val * sc.x + partner * sc.y);
            bf16* dst = (seg == 0) ? Qr : Kr;
            dst[(bh * T_SEQ + t) * HD + d] = __float2bfloat16(outv);
          }
        }
      }
    }
  }
}

// ---------------- flash attention (causal), S^T formulation, unpaired heavy-first grid ----
// One block = one (bh, q-tile). qt = 31 - blockIdx.x so heavy blocks dispatch first.
// Round-4 verified math: __expf softmax, SC=0.125, verified PV LDS round-trip.
__global__ __launch_bounds__(256) void attn_kernel(const bf16* __restrict__ Qr,
                                                   const bf16* __restrict__ Kr,
                                                   const bf16* __restrict__ Vt,
                                                   bf16* __restrict__ Y) {
  constexpr int DPAD = 72;
  __shared__ __align__(16) bf16 Ks[64 * DPAD];     // [k_local][d]
  __shared__ __align__(16) bf16 Vs[64 * DPAD];     // [d][k_local]
  __shared__ __align__(16) bf16 Ps[4][16 * DPAD];  // per-wave [q_local(16)][k(64)]
  const int qtile = 31 - blockIdx.x, bh = blockIdx.y;
  const int b = bh >> 4, h = bh & 15;
  const int tid = threadIdx.x, lane = tid & 63, wave = tid >> 6;
  const int quad = lane >> 4, c16 = lane & 15;
  const size_t hoff = (size_t)bh * T_SEQ * HD;
  const int row0 = tid >> 3, cp = tid & 7;  // staging: rows row0 / row0+32
  const int qbase = qtile * 64;
  const int qg = qbase + wave * 16 + c16;  // this lane's q row (softmax state owner)
  bf16x8 qf0 = *(const bf16x8*)&Qr[hoff + (size_t)qg * HD + quad * 8];
  bf16x8 qf1 = *(const bf16x8*)&Qr[hoff + (size_t)qg * HD + 32 + quad * 8];
  floatx4 o_acc[4] = {};  // o_acc[dt][r]: q=wave*16+quad*4+r, d=dt*16+c16
  float m_run = -1e30f, l_run = 0.f;
  // preload kt=0 K/V into regs
  bf16x8 kreg0 = *(const bf16x8*)&Kr[hoff + (size_t)row0 * HD + cp * 8];
  bf16x8 kreg1 = *(const bf16x8*)&Kr[hoff + (size_t)(row0 + 32) * HD + cp * 8];
  bf16x8 vreg0 = *(const bf16x8*)&Vt[hoff + (size_t)row0 * T_SEQ + cp * 8];
  bf16x8 vreg1 = *(const bf16x8*)&Vt[hoff + (size_t)(row0 + 32) * T_SEQ + cp * 8];
  for (int kt = 0; kt <= qtile; ++kt) {
    const int kbase = kt * 64;
    __syncthreads();  // prev-iter LDS consumers done
    *(bf16x8*)&Ks[row0 * DPAD + cp * 8] = kreg0;
    *(bf16x8*)&Ks[(row0 + 32) * DPAD + cp * 8] = kreg1;
    *(bf16x8*)&Vs[row0 * DPAD + cp * 8] = vreg0;
    *(bf16x8*)&Vs[(row0 + 32) * DPAD + cp * 8] = vreg1;
    __syncthreads();  // tiles visible
    // prefetch kt+1 after the barrier: compute phase hides the latency
    if (kt < qtile) {
      const int nb = kbase + 64;
      kreg0 = *(const bf16x8*)&Kr[hoff + (size_t)(nb + row0) * HD + cp * 8];
      kreg1 = *(const bf16x8*)&Kr[hoff + (size_t)(nb + row0 + 32) * HD + cp * 8];
      vreg0 = *(const bf16x8*)&Vt[hoff + (size_t)row0 * T_SEQ + nb + cp * 8];
      vreg1 = *(const bf16x8*)&Vt[hoff + (size_t)(row0 + 32) * T_SEQ + nb + cp * 8];
    }
    // S^T[k_local][q] = K . Q^T : A-frag = K rows, B-frag = Q rows
    floatx4 s[4];
#pragma unroll
    for (int nt = 0; nt < 4; nt++) {
      bf16x8 kf0 = *(const bf16x8*)&Ks[(nt * 16 + c16) * DPAD + quad * 8];
      bf16x8 kf1 = *(const bf16x8*)&Ks[(nt * 16 + c16) * DPAD + 32 + quad * 8];
      floatx4 z = {0.f, 0.f, 0.f, 0.f};
      z = __builtin_amdgcn_mfma_f32_16x16x32_bf16(kf0, qf0, z, 0, 0, 0);
      z = __builtin_amdgcn_mfma_f32_16x16x32_bf16(kf1, qf1, z, 0, 0, 0);
      s[nt] = z;  // row = k_local = nt*16+quad*4+r, col = q = c16
    }
    const bool diag = (kt == qtile);
    float mloc = -1e30f;
#pragma unroll
    for (int nt = 0; nt < 4; nt++)
#pragma unroll
      for (int r = 0; r < 4; r++) {
        float v = s[nt][r] * 0.125f;
        if (diag) {
          int kg = kbase + nt * 16 + quad * 4 + r;
          v = (kg <= qg) ? v : -1e30f;
        }
        s[nt][r] = v;
        mloc = fmaxf(mloc, v);
      }
    mloc = fmaxf(mloc, __shfl_xor(mloc, 16, 64));
    mloc = fmaxf(mloc, __shfl_xor(mloc, 32, 64));
    float mn = fmaxf(m_run, mloc);
    float alpha = __expf(m_run - mn);
    m_run = mn;
    float lloc = 0.f;
    union { bf16 h[4]; s16x4 sv; } ph[4];
#pragma unroll
    for (int nt = 0; nt < 4; nt++)
#pragma unroll
      for (int r = 0; r < 4; r++) {
        float pp = __expf(s[nt][r] - mn);
        lloc += pp;
        ph[nt].h[r] = __float2bfloat16(pp);
      }
    lloc += __shfl_xor(lloc, 16, 64);
    lloc += __shfl_xor(lloc, 32, 64);
    l_run = l_run * alpha + lloc;
    // P[q=c16][k=nt*16+quad*4+r] -> Ps[wave][q][k]
#pragma unroll
    for (int nt = 0; nt < 4; nt++)
      *(s16x4*)&Ps[wave][c16 * DPAD + nt * 16 + quad * 4] = ph[nt].sv;
    // broadcast alpha from state-lane (c16 = quad*4+r) to o_acc rows
    float a_bc[4];
#pragma unroll
    for (int r = 0; r < 4; r++) a_bc[r] = __shfl(alpha, quad * 4 + r, 16);
#pragma unroll
    for (int dt = 0; dt < 4; dt++)
#pragma unroll
      for (int r = 0; r < 4; r++) o_acc[dt][r] *= a_bc[r];
    // O += P.V  (A=P from Ps, B=V^T rows from Vs)
    bf16x8 pf0 = *(const bf16x8*)&Ps[wave][c16 * DPAD + quad * 8];
    bf16x8 pf1 = *(const bf16x8*)&Ps[wave][c16 * DPAD + 32 + quad * 8];
#pragma unroll
    for (int dt = 0; dt < 4; dt++) {
      bf16x8 vf0 = *(const bf16x8*)&Vs[(dt * 16 + c16) * DPAD + quad * 8];
      bf16x8 vf1 = *(const bf16x8*)&Vs[(dt * 16 + c16) * DPAD + 32 + quad * 8];
      o_acc[dt] = __builtin_amdgcn_mfma_f32_16x16x32_bf16(pf0, vf0, o_acc[dt], 0, 0, 0);
      o_acc[dt] = __builtin_amdgcn_mfma_f32_16x16x32_bf16(pf1, vf1, o_acc[dt], 0, 0, 0);
    }
  }
  // epilogue: broadcast 1/l to rows, store O[q][d]
  float linv = 1.0f / l_run;
  float l_bc[4];
#pragma unroll
  for (int r = 0; r < 4; r++) l_bc[r] = __shfl(linv, quad * 4 + r, 16);
#pragma unroll
  for (int dt = 0; dt < 4; dt++)
#pragma unroll
    for (int r = 0; r < 4; r++) {
      int t = qbase + wave * 16 + quad * 4 + r;
      Y[((size_t)(b * T_SEQ + t)) * CDIM + h * HD + dt * 16 + c16] =
          __float2bfloat16(o_acc[dt][r] * l_bc[r]);
    }
}

// ---------------- launch ----------------
extern "C" void kernel_launch(void* const* d_in, const int* in_sizes, int n_in,
                              void* d_out, int out_size, void* d_ws, size_t ws_size,
                              hipStream_t stream) {
  const float* x    = (const float*)d_in[0];   // [B,T,C] fp32
  const float* Wqkv = (const float*)d_in[2];   // [C,3C] fp32
  const float* Wo   = (const float*)d_in[3];   // [C,C] fp32
  float* out = (float*)d_out;                  // [B,T,C] fp32

  bf16* ws    = (bf16*)d_ws;
  bf16* Xb    = ws;                          // [4096][1024]
  bf16* WqkvT = Xb + 4194304;                // [3072][1024]
  bf16* WoT   = WqkvT + 3072 * 1024;         // [1024][1024]
  bf16* Qr    = WoT + 1024 * 1024;           // [B,H,T,D]
  bf16* Kr    = Qr + 4194304;                // [B,H,T,D]
  bf16* Vt    = Kr + 4194304;                // [B,H,D,T]
  bf16* Y     = Vt + 4194304;                // [B,T,C]
  float2* tab = (float2*)(Y + 4194304);      // [T][32]

  cast_bf16_kernel<<<4194304 / (256 * 4), 256, 0, stream>>>(x, Xb);
  transpose_cast<<<dim3(3072 / 32, 1024 / 32), 256, 0, stream>>>(Wqkv, WqkvT, 1024, 3072);
  transpose_cast<<<dim3(1024 / 32, 1024 / 32), 256, 0, stream>>>(Wo, WoT, 1024, 1024);
  rope_tab_kernel<<<65536 / 256, 256, 0, stream>>>(tab);
  gemm_bt<1><<<dim3(3072 / 128, 4096 / 128), 256, 0, stream>>>(
      Xb, WqkvT, nullptr, tab, Qr, Kr, Vt, 4096, 3072, 1024);
  attn_kernel<<<dim3(32, 32), 256, 0, stream>>>(Qr, Kr, Vt, Y);
  gemm_bt<0><<<dim3(1024 / 128, 4096 / 128), 256, 0, stream>>>(
      Y, WoT, out, nullptr, nullptr, nullptr, nullptr, 4096, 1024, 1024);
}

// Round 7
// 214.106 us; speedup vs baseline: 1.1749x; 1.1749x over previous
//
#include <hip/hip_runtime.h>
#include <hip/hip_bf16.h>

typedef __bf16 bf16x8 __attribute__((ext_vector_type(8)));
typedef short s16x4 __attribute__((ext_vector_type(4)));
typedef float floatx4 __attribute__((ext_vector_type(4)));
typedef __hip_bfloat16 bf16;

#define T_SEQ 2048
#define NH 16
#define HD 64
#define CDIM 1024

// async global->LDS, 16B/lane. ldsbase MUST be wave-uniform; HW stores lane i at ldsbase+i*16.
__device__ __forceinline__ void gload16(const bf16* g, bf16* ldsbase) {
  __builtin_amdgcn_global_load_lds((const __attribute__((address_space(1))) void*)g,
                                   (__attribute__((address_space(3))) void*)ldsbase, 16, 0, 0);
}

// ---------------- fp32 -> bf16 cast (4 elems/thread) ----------------
__global__ __launch_bounds__(256) void cast_bf16_kernel(const float* __restrict__ in,
                                                        bf16* __restrict__ out) {
  int i = blockIdx.x * 256 + threadIdx.x;
  const float4 v = ((const float4*)in)[i];
  union { bf16 h[4]; uint2 u; } p;
  p.h[0] = __float2bfloat16(v.x);
  p.h[1] = __float2bfloat16(v.y);
  p.h[2] = __float2bfloat16(v.z);
  p.h[3] = __float2bfloat16(v.w);
  ((uint2*)out)[i] = p.u;
}

// ---------------- LDS-tiled transpose + cast: out_bf16[Cc][R] = in_f32[R][Cc] ----------------
__global__ __launch_bounds__(256) void transpose_cast(const float* __restrict__ in,
                                                      bf16* __restrict__ out,
                                                      int R, int Cc) {
  __shared__ float tile[32][33];
  const int bx = blockIdx.x * 32;
  const int by = blockIdx.y * 32;
  const int tx = threadIdx.x & 31, ty = threadIdx.x >> 5;
#pragma unroll
  for (int i = 0; i < 32; i += 8)
    tile[ty + i][tx] = in[(size_t)(by + ty + i) * Cc + bx + tx];
  __syncthreads();
#pragma unroll
  for (int i = 0; i < 32; i += 8)
    out[(size_t)(bx + ty + i) * R + by + tx] = __float2bfloat16(tile[tx][ty + i]);
}

// ---------------- RoPE table ----------------
__global__ void rope_tab_kernel(float2* __restrict__ tab) {
  int idx = blockIdx.x * 256 + threadIdx.x;  // 2048*32
  int t = idx >> 5, j = idx & 31;
  float w = exp2f(-13.287712379549449f * (float)(2 * j + 1) * (1.0f / 64.0f));
  float ang = (float)(t + 1) * w;
  tab[idx] = make_float2(cosf(ang), sinf(ang));
}

// ---------------- 128x128x(BK=32) bf16 MFMA GEMM, B^T input, global_load_lds staging ----
template <int MODE>
__global__ __launch_bounds__(256) void gemm_bt(
    const bf16* __restrict__ A, const bf16* __restrict__ BT, float* __restrict__ CoutF,
    const float2* __restrict__ tab, bf16* __restrict__ Qr, bf16* __restrict__ Kr,
    bf16* __restrict__ Vt, int M, int N, int K) {
  constexpr int LDK = 32;  // unpadded: global_load_lds dest is lane-contiguous
  __shared__ __align__(16) bf16 As[128 * LDK];
  __shared__ __align__(16) bf16 Bs[128 * LDK];
  const int tid = threadIdx.x, lane = tid & 63, wave = tid >> 6;
  const int quad = lane >> 4, c16 = lane & 15;
  const int tile_m = blockIdx.y * 128, tile_n = blockIdx.x * 128;
  const int wm = (wave >> 1) * 64, wn = (wave & 1) * 64;
  const int r0 = tid >> 2, cp4 = tid & 3;
  bf16* ldsA0 = &As[wave * 512];           // wave-uniform bases (HW adds lane*16B)
  bf16* ldsA1 = &As[2048 + wave * 512];
  bf16* ldsB0 = &Bs[wave * 512];
  bf16* ldsB1 = &Bs[2048 + wave * 512];
  floatx4 acc[4][4] = {};
  for (int k0 = 0; k0 < K; k0 += 32) {
    __syncthreads();
    gload16(&A[(size_t)(tile_m + r0) * K + k0 + cp4 * 8], ldsA0);
    gload16(&A[(size_t)(tile_m + r0 + 64) * K + k0 + cp4 * 8], ldsA1);
    gload16(&BT[(size_t)(tile_n + r0) * K + k0 + cp4 * 8], ldsB0);
    gload16(&BT[(size_t)(tile_n + r0 + 64) * K + k0 + cp4 * 8], ldsB1);
    __syncthreads();
    bf16x8 af[4], bfr[4];
#pragma unroll
    for (int i = 0; i < 4; i++)
      af[i] = *(const bf16x8*)&As[(wm + i * 16 + c16) * LDK + quad * 8];
#pragma unroll
    for (int i = 0; i < 4; i++)
      bfr[i] = *(const bf16x8*)&Bs[(wn + i * 16 + c16) * LDK + quad * 8];
#pragma unroll
    for (int mi = 0; mi < 4; mi++)
#pragma unroll
      for (int ni = 0; ni < 4; ni++)
        acc[mi][ni] = __builtin_amdgcn_mfma_f32_16x16x32_bf16(af[mi], bfr[ni], acc[mi][ni], 0, 0, 0);
  }
  // C/D layout (m89): col = lane&15, row = quad*4 + reg
  if (MODE == 0) {
#pragma unroll
    for (int mi = 0; mi < 4; mi++) {
      int row0 = tile_m + wm + mi * 16 + quad * 4;
#pragma unroll
      for (int ni = 0; ni < 4; ni++) {
        int col = tile_n + wn + ni * 16 + c16;
#pragma unroll
        for (int r = 0; r < 4; r++)
          CoutF[(size_t)(row0 + r) * N + col] = acc[mi][ni][r];
      }
    }
  } else {
#pragma unroll
    for (int ni = 0; ni < 4; ni++) {
      int colg = tile_n + wn + ni * 16 + c16;
      int seg = colg >> 10;  // 0=q 1=k 2=v
      int cc = colg & 1023;
      int h = cc >> 6, d = cc & 63, j = d >> 1;
#pragma unroll
      for (int mi = 0; mi < 4; mi++) {
        int row0 = tile_m + wm + mi * 16 + quad * 4;
#pragma unroll
        for (int r = 0; r < 4; r++) {
          int rowg = row0 + r;
          int b = rowg >> 11, t = rowg & 2047;
          float val = acc[mi][ni][r];
          float partner = __shfl_xor(val, 1, 64);
          size_t bh = (size_t)(b * NH + h);
          if (seg == 2) {
            Vt[(bh * HD + d) * T_SEQ + t] = __float2bfloat16(val);
          } else {
            float2 sc = tab[t * 32 + j];
            float outv = ((d & 1) == 0) ? (val * sc.x - partner * sc.y)
                                        : (val * sc.x + partner * sc.y);
            bf16* dst = (seg == 0) ? Qr : Kr;
            dst[(bh * T_SEQ + t) * HD + d] = __float2bfloat16(outv);
          }
        }
      }
    }
  }
}

// ---------------- flash attention (causal), S^T formulation, GLOBALLY heavy-first ----
// 1-D grid of 1024: qtile = 31 - (x>>5) (all 32 bh of the heaviest tile first, then next...).
// Tail blocks are the 1-iter ones -> near-balanced makespan with ~4 blocks/CU steady state.
__global__ __launch_bounds__(256) void attn_kernel(const bf16* __restrict__ Qr,
                                                   const bf16* __restrict__ Kr,
                                                   const bf16* __restrict__ Vt,
                                                   bf16* __restrict__ Y) {
  constexpr int DPAD = 72;
  __shared__ __align__(16) bf16 Ks[64 * DPAD];     // [k_local][d]
  __shared__ __align__(16) bf16 Vs[64 * DPAD];     // [d][k_local]
  __shared__ __align__(16) bf16 Ps[4][16 * DPAD];  // per-wave [q_local(16)][k(64)]
  const int qtile = 31 - (blockIdx.x >> 5), bh = blockIdx.x & 31;
  const int b = bh >> 4, h = bh & 15;
  const int tid = threadIdx.x, lane = tid & 63, wave = tid >> 6;
  const int quad = lane >> 4, c16 = lane & 15;
  const size_t hoff = (size_t)bh * T_SEQ * HD;
  const int row0 = tid >> 3, cp = tid & 7;  // staging: rows row0 / row0+32
  const int qbase = qtile * 64;
  const int qg = qbase + wave * 16 + c16;  // this lane's q row (softmax state owner)
  bf16x8 qf0 = *(const bf16x8*)&Qr[hoff + (size_t)qg * HD + quad * 8];
  bf16x8 qf1 = *(const bf16x8*)&Qr[hoff + (size_t)qg * HD + 32 + quad * 8];
  floatx4 o_acc[4] = {};  // o_acc[dt][r]: q=wave*16+quad*4+r, d=dt*16+c16
  float m_run = -1e30f, l_run = 0.f;
  // preload kt=0 K/V into regs
  bf16x8 kreg0 = *(const bf16x8*)&Kr[hoff + (size_t)row0 * HD + cp * 8];
  bf16x8 kreg1 = *(const bf16x8*)&Kr[hoff + (size_t)(row0 + 32) * HD + cp * 8];
  bf16x8 vreg0 = *(const bf16x8*)&Vt[hoff + (size_t)row0 * T_SEQ + cp * 8];
  bf16x8 vreg1 = *(const bf16x8*)&Vt[hoff + (size_t)(row0 + 32) * T_SEQ + cp * 8];
  for (int kt = 0; kt <= qtile; ++kt) {
    const int kbase = kt * 64;
    __syncthreads();  // prev-iter LDS consumers done
    *(bf16x8*)&Ks[row0 * DPAD + cp * 8] = kreg0;
    *(bf16x8*)&Ks[(row0 + 32) * DPAD + cp * 8] = kreg1;
    *(bf16x8*)&Vs[row0 * DPAD + cp * 8] = vreg0;
    *(bf16x8*)&Vs[(row0 + 32) * DPAD + cp * 8] = vreg1;
    __syncthreads();  // tiles visible
    // prefetch kt+1 after the barrier: compute phase hides the latency
    if (kt < qtile) {
      const int nb = kbase + 64;
      kreg0 = *(const bf16x8*)&Kr[hoff + (size_t)(nb + row0) * HD + cp * 8];
      kreg1 = *(const bf16x8*)&Kr[hoff + (size_t)(nb + row0 + 32) * HD + cp * 8];
      vreg0 = *(const bf16x8*)&Vt[hoff + (size_t)row0 * T_SEQ + nb + cp * 8];
      vreg1 = *(const bf16x8*)&Vt[hoff + (size_t)(row0 + 32) * T_SEQ + nb + cp * 8];
    }
    // S^T[k_local][q] = K . Q^T : A-frag = K rows, B-frag = Q rows
    floatx4 s[4];
#pragma unroll
    for (int nt = 0; nt < 4; nt++) {
      bf16x8 kf0 = *(const bf16x8*)&Ks[(nt * 16 + c16) * DPAD + quad * 8];
      bf16x8 kf1 = *(const bf16x8*)&Ks[(nt * 16 + c16) * DPAD + 32 + quad * 8];
      floatx4 z = {0.f, 0.f, 0.f, 0.f};
      z = __builtin_amdgcn_mfma_f32_16x16x32_bf16(kf0, qf0, z, 0, 0, 0);
      z = __builtin_amdgcn_mfma_f32_16x16x32_bf16(kf1, qf1, z, 0, 0, 0);
      s[nt] = z;  // row = k_local = nt*16+quad*4+r, col = q = c16
    }
    const bool diag = (kt == qtile);
    float mloc = -1e30f;
#pragma unroll
    for (int nt = 0; nt < 4; nt++)
#pragma unroll
      for (int r = 0; r < 4; r++) {
        float v = s[nt][r] * 0.125f;
        if (diag) {
          int kg = kbase + nt * 16 + quad * 4 + r;
          v = (kg <= qg) ? v : -1e30f;
        }
        s[nt][r] = v;
        mloc = fmaxf(mloc, v);
      }
    mloc = fmaxf(mloc, __shfl_xor(mloc, 16, 64));
    mloc = fmaxf(mloc, __shfl_xor(mloc, 32, 64));
    float mn = fmaxf(m_run, mloc);
    float alpha = __expf(m_run - mn);
    m_run = mn;
    float lloc = 0.f;
    union { bf16 h[4]; s16x4 sv; } ph[4];
#pragma unroll
    for (int nt = 0; nt < 4; nt++)
#pragma unroll
      for (int r = 0; r < 4; r++) {
        float pp = __expf(s[nt][r] - mn);
        lloc += pp;
        ph[nt].h[r] = __float2bfloat16(pp);
      }
    lloc += __shfl_xor(lloc, 16, 64);
    lloc += __shfl_xor(lloc, 32, 64);
    l_run = l_run * alpha + lloc;
    // P[q=c16][k=nt*16+quad*4+r] -> Ps[wave][q][k]
#pragma unroll
    for (int nt = 0; nt < 4; nt++)
      *(s16x4*)&Ps[wave][c16 * DPAD + nt * 16 + quad * 4] = ph[nt].sv;
    // broadcast alpha from state-lane (c16 = quad*4+r) to o_acc rows
    float a_bc[4];
#pragma unroll
    for (int r = 0; r < 4; r++) a_bc[r] = __shfl(alpha, quad * 4 + r, 16);
#pragma unroll
    for (int dt = 0; dt < 4; dt++)
#pragma unroll
      for (int r = 0; r < 4; r++) o_acc[dt][r] *= a_bc[r];
    // O += P.V  (A=P from Ps, B=V^T rows from Vs)
    bf16x8 pf0 = *(const bf16x8*)&Ps[wave][c16 * DPAD + quad * 8];
    bf16x8 pf1 = *(const bf16x8*)&Ps[wave][c16 * DPAD + 32 + quad * 8];
#pragma unroll
    for (int dt = 0; dt < 4; dt++) {
      bf16x8 vf0 = *(const bf16x8*)&Vs[(dt * 16 + c16) * DPAD + quad * 8];
      bf16x8 vf1 = *(const bf16x8*)&Vs[(dt * 16 + c16) * DPAD + 32 + quad * 8];
      o_acc[dt] = __builtin_amdgcn_mfma_f32_16x16x32_bf16(pf0, vf0, o_acc[dt], 0, 0, 0);
      o_acc[dt] = __builtin_amdgcn_mfma_f32_16x16x32_bf16(pf1, vf1, o_acc[dt], 0, 0, 0);
    }
  }
  // epilogue: broadcast 1/l to rows, store O[q][d]
  float linv = 1.0f / l_run;
  float l_bc[4];
#pragma unroll
  for (int r = 0; r < 4; r++) l_bc[r] = __shfl(linv, quad * 4 + r, 16);
#pragma unroll
  for (int dt = 0; dt < 4; dt++)
#pragma unroll
    for (int r = 0; r < 4; r++) {
      int t = qbase + wave * 16 + quad * 4 + r;
      Y[((size_t)(b * T_SEQ + t)) * CDIM + h * HD + dt * 16 + c16] =
          __float2bfloat16(o_acc[dt][r] * l_bc[r]);
    }
}

// ---------------- launch ----------------
extern "C" void kernel_launch(void* const* d_in, const int* in_sizes, int n_in,
                              void* d_out, int out_size, void* d_ws, size_t ws_size,
                              hipStream_t stream) {
  const float* x    = (const float*)d_in[0];   // [B,T,C] fp32
  const float* Wqkv = (const float*)d_in[2];   // [C,3C] fp32
  const float* Wo   = (const float*)d_in[3];   // [C,C] fp32
  float* out = (float*)d_out;                  // [B,T,C] fp32

  bf16* ws    = (bf16*)d_ws;
  bf16* Xb    = ws;                          // [4096][1024]
  bf16* WqkvT = Xb + 4194304;                // [3072][1024]
  bf16* WoT   = WqkvT + 3072 * 1024;         // [1024][1024]
  bf16* Qr    = WoT + 1024 * 1024;           // [B,H,T,D]
  bf16* Kr    = Qr + 4194304;                // [B,H,T,D]
  bf16* Vt    = Kr + 4194304;                // [B,H,D,T]
  bf16* Y     = Vt + 4194304;                // [B,T,C]
  float2* tab = (float2*)(Y + 4194304);      // [T][32]

  cast_bf16_kernel<<<4194304 / (256 * 4), 256, 0, stream>>>(x, Xb);
  transpose_cast<<<dim3(3072 / 32, 1024 / 32), 256, 0, stream>>>(Wqkv, WqkvT, 1024, 3072);
  transpose_cast<<<dim3(1024 / 32, 1024 / 32), 256, 0, stream>>>(Wo, WoT, 1024, 1024);
  rope_tab_kernel<<<65536 / 256, 256, 0, stream>>>(tab);
  gemm_bt<1><<<dim3(3072 / 128, 4096 / 128), 256, 0, stream>>>(
      Xb, WqkvT, nullptr, tab, Qr, Kr, Vt, 4096, 3072, 1024);
  attn_kernel<<<dim3(1024), 256, 0, stream>>>(Qr, Kr, Vt, Y);
  gemm_bt<0><<<dim3(1024 / 128, 4096 / 128), 256, 0, stream>>>(
      Y, WoT, out, nullptr, nullptr, nullptr, nullptr, 4096, 1024, 1024);
}

// Round 8
// 208.335 us; speedup vs baseline: 1.2074x; 1.0277x over previous
//
#include <hip/hip_runtime.h>
#include <hip/hip_bf16.h>

typedef __bf16 bf16x8 __attribute__((ext_vector_type(8)));
typedef short s16x4 __attribute__((ext_vector_type(4)));
typedef float floatx4 __attribute__((ext_vector_type(4)));
typedef __hip_bfloat16 bf16;

#define T_SEQ 2048
#define NH 16
#define HD 64
#define CDIM 1024

// async global->LDS, 16B/lane. ldsbase MUST be wave-uniform; HW stores lane i at ldsbase+i*16.
__device__ __forceinline__ void gload16(const bf16* g, bf16* ldsbase) {
  __builtin_amdgcn_global_load_lds((const __attribute__((address_space(1))) void*)g,
                                   (__attribute__((address_space(3))) void*)ldsbase, 16, 0, 0);
}

// ---------------- fused prep: cast x, transpose+cast Wqkv & Wo, rope table ----------------
// blocks [0,4096): cast x (1024 f32/block)
// blocks [4096,7168): transpose Wqkv tile (bx=t%96, by=t/96)
// blocks [7168,8192): transpose Wo tile (bx=t%32, by=t/32)
// blocks [8192,8448): rope table
__global__ __launch_bounds__(256) void prep_kernel(const float* __restrict__ x,
                                                   const float* __restrict__ Wqkv,
                                                   const float* __restrict__ Wo,
                                                   bf16* __restrict__ Xb,
                                                   bf16* __restrict__ WqkvT,
                                                   bf16* __restrict__ WoT,
                                                   float2* __restrict__ tab) {
  __shared__ float tile[32][33];
  const int bid = blockIdx.x, tid = threadIdx.x;
  if (bid < 4096) {
    int i = bid * 256 + tid;
    const float4 v = ((const float4*)x)[i];
    union { bf16 h[4]; uint2 u; } pk;
    pk.h[0] = __float2bfloat16(v.x);
    pk.h[1] = __float2bfloat16(v.y);
    pk.h[2] = __float2bfloat16(v.z);
    pk.h[3] = __float2bfloat16(v.w);
    ((uint2*)Xb)[i] = pk.u;
  } else if (bid < 8192) {
    const float* in;
    bf16* out;
    int bx, by, R, Cc;
    if (bid < 7168) {
      int t = bid - 4096;
      in = Wqkv; out = WqkvT; R = 1024; Cc = 3072;
      bx = (t % 96) * 32; by = (t / 96) * 32;
    } else {
      int t = bid - 7168;
      in = Wo; out = WoT; R = 1024; Cc = 1024;
      bx = (t & 31) * 32; by = (t >> 5) * 32;
    }
    const int tx = tid & 31, ty = tid >> 5;
#pragma unroll
    for (int i = 0; i < 32; i += 8)
      tile[ty + i][tx] = in[(size_t)(by + ty + i) * Cc + bx + tx];
    __syncthreads();
#pragma unroll
    for (int i = 0; i < 32; i += 8)
      out[(size_t)(bx + ty + i) * R + by + tx] = __float2bfloat16(tile[tx][ty + i]);
  } else {
    int idx = (bid - 8192) * 256 + tid;  // 2048*32
    int t = idx >> 5, j = idx & 31;
    float w = exp2f(-13.287712379549449f * (float)(2 * j + 1) * (1.0f / 64.0f));
    float ang = (float)(t + 1) * w;
    tab[idx] = make_float2(cosf(ang), sinf(ang));
  }
}

// ---------------- 128x128x(BK=32) bf16 MFMA GEMM, B^T input, global_load_lds staging ----
// XOR chunk swizzle: LDS slot (r,c) holds global chunk c ^ ((r>>1)&3) -> frag reads 2-way banks.
template <int MODE>
__global__ __launch_bounds__(256) void gemm_bt(
    const bf16* __restrict__ A, const bf16* __restrict__ BT, float* __restrict__ CoutF,
    const float2* __restrict__ tab, bf16* __restrict__ Qr, bf16* __restrict__ Kr,
    bf16* __restrict__ Vt, int M, int N, int K) {
  constexpr int LDK = 32;  // unpadded: global_load_lds dest is lane-contiguous
  __shared__ __align__(16) bf16 As[128 * LDK];
  __shared__ __align__(16) bf16 Bs[128 * LDK];
  const int tid = threadIdx.x, lane = tid & 63, wave = tid >> 6;
  const int quad = lane >> 4, c16 = lane & 15;
  const int tile_m = blockIdx.y * 128, tile_n = blockIdx.x * 128;
  const int wm = (wave >> 1) * 64, wn = (wave & 1) * 64;
  const int r0 = tid >> 2, cp4 = tid & 3;
  const int csw = (cp4 ^ ((r0 >> 1) & 3)) * 8;  // swizzled source chunk (same for r0 and r0+64)
  const int swr = (quad ^ ((c16 >> 1) & 3)) * 8;  // swizzled read slot (global chunk = quad)
  bf16* ldsA0 = &As[wave * 512];           // wave-uniform bases (HW adds lane*16B)
  bf16* ldsA1 = &As[2048 + wave * 512];
  bf16* ldsB0 = &Bs[wave * 512];
  bf16* ldsB1 = &Bs[2048 + wave * 512];
  floatx4 acc[4][4] = {};
  for (int k0 = 0; k0 < K; k0 += 32) {
    __syncthreads();
    gload16(&A[(size_t)(tile_m + r0) * K + k0 + csw], ldsA0);
    gload16(&A[(size_t)(tile_m + r0 + 64) * K + k0 + csw], ldsA1);
    gload16(&BT[(size_t)(tile_n + r0) * K + k0 + csw], ldsB0);
    gload16(&BT[(size_t)(tile_n + r0 + 64) * K + k0 + csw], ldsB1);
    __syncthreads();
    bf16x8 af[4], bfr[4];
#pragma unroll
    for (int i = 0; i < 4; i++)
      af[i] = *(const bf16x8*)&As[(wm + i * 16 + c16) * LDK + swr];
#pragma unroll
    for (int i = 0; i < 4; i++)
      bfr[i] = *(const bf16x8*)&Bs[(wn + i * 16 + c16) * LDK + swr];
#pragma unroll
    for (int mi = 0; mi < 4; mi++)
#pragma unroll
      for (int ni = 0; ni < 4; ni++)
        acc[mi][ni] = __builtin_amdgcn_mfma_f32_16x16x32_bf16(af[mi], bfr[ni], acc[mi][ni], 0, 0, 0);
  }
  // C/D layout (m89): col = lane&15, row = quad*4 + reg
  if (MODE == 0) {
#pragma unroll
    for (int mi = 0; mi < 4; mi++) {
      int row0 = tile_m + wm + mi * 16 + quad * 4;
#pragma unroll
      for (int ni = 0; ni < 4; ni++) {
        int col = tile_n + wn + ni * 16 + c16;
#pragma unroll
        for (int r = 0; r < 4; r++)
          CoutF[(size_t)(row0 + r) * N + col] = acc[mi][ni][r];
      }
    }
  } else {
#pragma unroll
    for (int ni = 0; ni < 4; ni++) {
      int colg = tile_n + wn + ni * 16 + c16;
      int seg = colg >> 10;  // 0=q 1=k 2=v
      int cc = colg & 1023;
      int h = cc >> 6, d = cc & 63, j = d >> 1;
#pragma unroll
      for (int mi = 0; mi < 4; mi++) {
        int row0 = tile_m + wm + mi * 16 + quad * 4;
#pragma unroll
        for (int r = 0; r < 4; r++) {
          int rowg = row0 + r;
          int b = rowg >> 11, t = rowg & 2047;
          float val = acc[mi][ni][r];
          float partner = __shfl_xor(val, 1, 64);
          size_t bh = (size_t)(b * NH + h);
          if (seg == 2) {
            Vt[(bh * HD + d) * T_SEQ + t] = __float2bfloat16(val);
          } else {
            float2 sc = tab[t * 32 + j];
            float outv = ((d & 1) == 0) ? (val * sc.x - partner * sc.y)
                                        : (val * sc.x + partner * sc.y);
            bf16* dst = (seg == 0) ? Qr : Kr;
            dst[(bh * T_SEQ + t) * HD + d] = __float2bfloat16(outv);
          }
        }
      }
    }
  }
}

// ---------------- flash attention (causal), S^T, heavy-first, double-buffered LDS ----------
// 1 barrier/iter: prefetch global->regs at iter start (latency hidden by compute),
// regs->LDS buf[cur^1] at iter end, single barrier.
__global__ __launch_bounds__(256) void attn_kernel(const bf16* __restrict__ Qr,
                                                   const bf16* __restrict__ Kr,
                                                   const bf16* __restrict__ Vt,
                                                   bf16* __restrict__ Y) {
  constexpr int DPAD = 68;  // 136B rows: 16B-aligned; frag reads 2-way banks, writes 4-way
  __shared__ __align__(16) bf16 Ks[2][64 * DPAD];  // [buf][k_local][d]
  __shared__ __align__(16) bf16 Vs[2][64 * DPAD];  // [buf][d][k_local]
  __shared__ __align__(16) bf16 Ps[4][16 * DPAD];  // per-wave [q_local(16)][k(64)]
  const int qtile = 31 - (blockIdx.x >> 5), bh = blockIdx.x & 31;
  const int b = bh >> 4, h = bh & 15;
  const int tid = threadIdx.x, lane = tid & 63, wave = tid >> 6;
  const int quad = lane >> 4, c16 = lane & 15;
  const size_t hoff = (size_t)bh * T_SEQ * HD;
  const int row0 = tid >> 3, cp = tid & 7;  // staging: rows row0 / row0+32
  const int qbase = qtile * 64;
  const int qg = qbase + wave * 16 + c16;  // this lane's q row (softmax state owner)
  bf16x8 qf0 = *(const bf16x8*)&Qr[hoff + (size_t)qg * HD + quad * 8];
  bf16x8 qf1 = *(const bf16x8*)&Qr[hoff + (size_t)qg * HD + 32 + quad * 8];
  floatx4 o_acc[4] = {};  // o_acc[dt][r]: q=wave*16+quad*4+r, d=dt*16+c16
  float m_run = -1e30f, l_run = 0.f;
  // preload kt=0 K/V into regs, stage into buf 0
  bf16x8 kreg0 = *(const bf16x8*)&Kr[hoff + (size_t)row0 * HD + cp * 8];
  bf16x8 kreg1 = *(const bf16x8*)&Kr[hoff + (size_t)(row0 + 32) * HD + cp * 8];
  bf16x8 vreg0 = *(const bf16x8*)&Vt[hoff + (size_t)row0 * T_SEQ + cp * 8];
  bf16x8 vreg1 = *(const bf16x8*)&Vt[hoff + (size_t)(row0 + 32) * T_SEQ + cp * 8];
  *(bf16x8*)&Ks[0][row0 * DPAD + cp * 8] = kreg0;
  *(bf16x8*)&Ks[0][(row0 + 32) * DPAD + cp * 8] = kreg1;
  *(bf16x8*)&Vs[0][row0 * DPAD + cp * 8] = vreg0;
  *(bf16x8*)&Vs[0][(row0 + 32) * DPAD + cp * 8] = vreg1;
  __syncthreads();
  for (int kt = 0; kt <= qtile; ++kt) {
    const int kbase = kt * 64;
    const int cur = kt & 1;
    // issue next tile's global loads now; drained at the LDS write below (compute hides latency)
    if (kt < qtile) {
      const int nb = kbase + 64;
      kreg0 = *(const bf16x8*)&Kr[hoff + (size_t)(nb + row0) * HD + cp * 8];
      kreg1 = *(const bf16x8*)&Kr[hoff + (size_t)(nb + row0 + 32) * HD + cp * 8];
      vreg0 = *(const bf16x8*)&Vt[hoff + (size_t)row0 * T_SEQ + nb + cp * 8];
      vreg1 = *(const bf16x8*)&Vt[hoff + (size_t)(row0 + 32) * T_SEQ + nb + cp * 8];
    }
    // S^T[k_local][q] = K . Q^T : A-frag = K rows, B-frag = Q rows
    floatx4 s[4];
#pragma unroll
    for (int nt = 0; nt < 4; nt++) {
      bf16x8 kf0 = *(const bf16x8*)&Ks[cur][(nt * 16 + c16) * DPAD + quad * 8];
      bf16x8 kf1 = *(const bf16x8*)&Ks[cur][(nt * 16 + c16) * DPAD + 32 + quad * 8];
      floatx4 z = {0.f, 0.f, 0.f, 0.f};
      z = __builtin_amdgcn_mfma_f32_16x16x32_bf16(kf0, qf0, z, 0, 0, 0);
      z = __builtin_amdgcn_mfma_f32_16x16x32_bf16(kf1, qf1, z, 0, 0, 0);
      s[nt] = z;  // row = k_local = nt*16+quad*4+r, col = q = c16
    }
    const bool diag = (kt == qtile);
    float mloc = -1e30f;
#pragma unroll
    for (int nt = 0; nt < 4; nt++)
#pragma unroll
      for (int r = 0; r < 4; r++) {
        float v = s[nt][r] * 0.125f;
        if (diag) {
          int kg = kbase + nt * 16 + quad * 4 + r;
          v = (kg <= qg) ? v : -1e30f;
        }
        s[nt][r] = v;
        mloc = fmaxf(mloc, v);
      }
    mloc = fmaxf(mloc, __shfl_xor(mloc, 16, 64));
    mloc = fmaxf(mloc, __shfl_xor(mloc, 32, 64));
    float mn = fmaxf(m_run, mloc);
    float alpha = __expf(m_run - mn);
    m_run = mn;
    float lloc = 0.f;
    union { bf16 h[4]; s16x4 sv; } ph[4];
#pragma unroll
    for (int nt = 0; nt < 4; nt++)
#pragma unroll
      for (int r = 0; r < 4; r++) {
        float pp = __expf(s[nt][r] - mn);
        lloc += pp;
        ph[nt].h[r] = __float2bfloat16(pp);
      }
    lloc += __shfl_xor(lloc, 16, 64);
    lloc += __shfl_xor(lloc, 32, 64);
    l_run = l_run * alpha + lloc;
    // P[q=c16][k=nt*16+quad*4+r] -> Ps[wave][q][k] (per-wave region, no barrier needed)
#pragma unroll
    for (int nt = 0; nt < 4; nt++)
      *(s16x4*)&Ps[wave][c16 * DPAD + nt * 16 + quad * 4] = ph[nt].sv;
    // broadcast alpha from state-lane (c16 = quad*4+r) to o_acc rows
    float a_bc[4];
#pragma unroll
    for (int r = 0; r < 4; r++) a_bc[r] = __shfl(alpha, quad * 4 + r, 16);
#pragma unroll
    for (int dt = 0; dt < 4; dt++)
#pragma unroll
      for (int r = 0; r < 4; r++) o_acc[dt][r] *= a_bc[r];
    // O += P.V  (A=P from Ps, B=V^T rows from Vs[cur])
    bf16x8 pf0 = *(const bf16x8*)&Ps[wave][c16 * DPAD + quad * 8];
    bf16x8 pf1 = *(const bf16x8*)&Ps[wave][c16 * DPAD + 32 + quad * 8];
#pragma unroll
    for (int dt = 0; dt < 4; dt++) {
      bf16x8 vf0 = *(const bf16x8*)&Vs[cur][(dt * 16 + c16) * DPAD + quad * 8];
      bf16x8 vf1 = *(const bf16x8*)&Vs[cur][(dt * 16 + c16) * DPAD + 32 + quad * 8];
      o_acc[dt] = __builtin_amdgcn_mfma_f32_16x16x32_bf16(pf0, vf0, o_acc[dt], 0, 0, 0);
      o_acc[dt] = __builtin_amdgcn_mfma_f32_16x16x32_bf16(pf1, vf1, o_acc[dt], 0, 0, 0);
    }
    // stage next tile into the other buffer; buf[cur^1]'s readers finished before the
    // barrier at end of iter kt-1, so writing here is race-free.
    if (kt < qtile) {
      const int nxt = cur ^ 1;
      *(bf16x8*)&Ks[nxt][row0 * DPAD + cp * 8] = kreg0;
      *(bf16x8*)&Ks[nxt][(row0 + 32) * DPAD + cp * 8] = kreg1;
      *(bf16x8*)&Vs[nxt][row0 * DPAD + cp * 8] = vreg0;
      *(bf16x8*)&Vs[nxt][(row0 + 32) * DPAD + cp * 8] = vreg1;
    }
    __syncthreads();  // single barrier per iter
  }
  // epilogue: broadcast 1/l to rows, store O[q][d]
  float linv = 1.0f / l_run;
  float l_bc[4];
#pragma unroll
  for (int r = 0; r < 4; r++) l_bc[r] = __shfl(linv, quad * 4 + r, 16);
#pragma unroll
  for (int dt = 0; dt < 4; dt++)
#pragma unroll
    for (int r = 0; r < 4; r++) {
      int t = qbase + wave * 16 + quad * 4 + r;
      Y[((size_t)(b * T_SEQ + t)) * CDIM + h * HD + dt * 16 + c16] =
          __float2bfloat16(o_acc[dt][r] * l_bc[r]);
    }
}

// ---------------- launch ----------------
extern "C" void kernel_launch(void* const* d_in, const int* in_sizes, int n_in,
                              void* d_out, int out_size, void* d_ws, size_t ws_size,
                              hipStream_t stream) {
  const float* x    = (const float*)d_in[0];   // [B,T,C] fp32
  const float* Wqkv = (const float*)d_in[2];   // [C,3C] fp32
  const float* Wo   = (const float*)d_in[3];   // [C,C] fp32
  float* out = (float*)d_out;                  // [B,T,C] fp32

  bf16* ws    = (bf16*)d_ws;
  bf16* Xb    = ws;                          // [4096][1024]
  bf16* WqkvT = Xb + 4194304;                // [3072][1024]
  bf16* WoT   = WqkvT + 3072 * 1024;         // [1024][1024]
  bf16* Qr    = WoT + 1024 * 1024;           // [B,H,T,D]
  bf16* Kr    = Qr + 4194304;                // [B,H,T,D]
  bf16* Vt    = Kr + 4194304;                // [B,H,D,T]
  bf16* Y     = Vt + 4194304;                // [B,T,C]
  float2* tab = (float2*)(Y + 4194304);      // [T][32]

  prep_kernel<<<dim3(8448), 256, 0, stream>>>(x, Wqkv, Wo, Xb, WqkvT, WoT, tab);
  gemm_bt<1><<<dim3(3072 / 128, 4096 / 128), 256, 0, stream>>>(
      Xb, WqkvT, nullptr, tab, Qr, Kr, Vt, 4096, 3072, 1024);
  attn_kernel<<<dim3(1024), 256, 0, stream>>>(Qr, Kr, Vt, Y);
  gemm_bt<0><<<dim3(1024 / 128, 4096 / 128), 256, 0, stream>>>(
      Y, WoT, out, nullptr, nullptr, nullptr, nullptr, 4096, 1024, 1024);
}

// Round 9
// 200.108 us; speedup vs baseline: 1.2570x; 1.0411x over previous
//
#include <hip/hip_runtime.h>
#include <hip/hip_bf16.h>

typedef __bf16 bf16x8 __attribute__((ext_vector_type(8)));
typedef short s16x4 __attribute__((ext_vector_type(4)));
typedef float floatx4 __attribute__((ext_vector_type(4)));
typedef __hip_bfloat16 bf16;

#define T_SEQ 2048
#define NH 16
#define HD 64
#define CDIM 1024

// async global->LDS, 16B/lane. ldsbase MUST be wave-uniform; HW stores lane i at ldsbase+i*16.
__device__ __forceinline__ void gload16(const bf16* g, bf16* ldsbase) {
  __builtin_amdgcn_global_load_lds((const __attribute__((address_space(1))) void*)g,
                                   (__attribute__((address_space(3))) void*)ldsbase, 16, 0, 0);
}

// ---------------- fused prep: cast x, transpose+cast Wqkv & Wo, rope table ----------------
__global__ __launch_bounds__(256) void prep_kernel(const float* __restrict__ x,
                                                   const float* __restrict__ Wqkv,
                                                   const float* __restrict__ Wo,
                                                   bf16* __restrict__ Xb,
                                                   bf16* __restrict__ WqkvT,
                                                   bf16* __restrict__ WoT,
                                                   float2* __restrict__ tab) {
  __shared__ float tile[32][33];
  const int bid = blockIdx.x, tid = threadIdx.x;
  if (bid < 4096) {
    int i = bid * 256 + tid;
    const float4 v = ((const float4*)x)[i];
    union { bf16 h[4]; uint2 u; } pk;
    pk.h[0] = __float2bfloat16(v.x);
    pk.h[1] = __float2bfloat16(v.y);
    pk.h[2] = __float2bfloat16(v.z);
    pk.h[3] = __float2bfloat16(v.w);
    ((uint2*)Xb)[i] = pk.u;
  } else if (bid < 8192) {
    const float* in;
    bf16* out;
    int bx, by, R, Cc;
    if (bid < 7168) {
      int t = bid - 4096;
      in = Wqkv; out = WqkvT; R = 1024; Cc = 3072;
      bx = (t % 96) * 32; by = (t / 96) * 32;
    } else {
      int t = bid - 7168;
      in = Wo; out = WoT; R = 1024; Cc = 1024;
      bx = (t & 31) * 32; by = (t >> 5) * 32;
    }
    const int tx = tid & 31, ty = tid >> 5;
#pragma unroll
    for (int i = 0; i < 32; i += 8)
      tile[ty + i][tx] = in[(size_t)(by + ty + i) * Cc + bx + tx];
    __syncthreads();
#pragma unroll
    for (int i = 0; i < 32; i += 8)
      out[(size_t)(bx + ty + i) * R + by + tx] = __float2bfloat16(tile[tx][ty + i]);
  } else {
    int idx = (bid - 8192) * 256 + tid;  // 2048*32
    int t = idx >> 5, j = idx & 31;
    float w = exp2f(-13.287712379549449f * (float)(2 * j + 1) * (1.0f / 64.0f));
    float ang = (float)(t + 1) * w;
    tab[idx] = make_float2(cosf(ang), sinf(ang));
  }
}

// ---------------- 128x128x(BK=64) bf16 MFMA GEMM, B^T input, global_load_lds staging ----
// 16 K-iters, 32 MFMA/iter: 2x barrier amortization vs BK=32.
// XOR chunk swizzle (8 chunks/row): LDS slot(r,c) holds global chunk c^(r&7);
// frag reads at slot (quad^(c16&7)) and ^4 -> 2-way-max banks; staging coalescing intact.
template <int MODE>
__global__ __launch_bounds__(256) void gemm_bt(
    const bf16* __restrict__ A, const bf16* __restrict__ BT, float* __restrict__ CoutF,
    const float2* __restrict__ tab, bf16* __restrict__ Qr, bf16* __restrict__ Kr,
    bf16* __restrict__ Vt, int M, int N, int K) {
  constexpr int LDK = 64;
  __shared__ __align__(16) bf16 As[128 * LDK];  // 16 KB
  __shared__ __align__(16) bf16 Bs[128 * LDK];  // 16 KB
  const int tid = threadIdx.x, lane = tid & 63, wave = tid >> 6;
  const int quad = lane >> 4, c16 = lane & 15;
  const int tile_m = blockIdx.y * 128, tile_n = blockIdx.x * 128;
  const int wm = (wave >> 1) * 64, wn = (wave & 1) * 64;
  const int r0 = tid >> 3;                       // staging row 0..31 (+32i)
  const int csw = ((tid & 7) ^ (r0 & 7)) * 8;    // swizzled global chunk offset (elems)
  const int s1 = (quad ^ (c16 & 7)) * 8;         // read slot, k-half 0
  const int s2 = s1 ^ 32;                        // read slot, k-half 1 (chunk quad+4)
  floatx4 acc[4][4] = {};
  for (int k0 = 0; k0 < K; k0 += 64) {
    __syncthreads();
#pragma unroll
    for (int i = 0; i < 4; i++) {
      gload16(&A[(size_t)(tile_m + r0 + i * 32) * K + k0 + csw], &As[i * 2048 + wave * 512]);
      gload16(&BT[(size_t)(tile_n + r0 + i * 32) * K + k0 + csw], &Bs[i * 2048 + wave * 512]);
    }
    __syncthreads();
    bf16x8 af[4], bfr[4];
    // k-half 0
#pragma unroll
    for (int i = 0; i < 4; i++) {
      af[i] = *(const bf16x8*)&As[(wm + i * 16 + c16) * LDK + s1];
      bfr[i] = *(const bf16x8*)&Bs[(wn + i * 16 + c16) * LDK + s1];
    }
#pragma unroll
    for (int mi = 0; mi < 4; mi++)
#pragma unroll
      for (int ni = 0; ni < 4; ni++)
        acc[mi][ni] = __builtin_amdgcn_mfma_f32_16x16x32_bf16(af[mi], bfr[ni], acc[mi][ni], 0, 0, 0);
    // k-half 1
#pragma unroll
    for (int i = 0; i < 4; i++) {
      af[i] = *(const bf16x8*)&As[(wm + i * 16 + c16) * LDK + s2];
      bfr[i] = *(const bf16x8*)&Bs[(wn + i * 16 + c16) * LDK + s2];
    }
#pragma unroll
    for (int mi = 0; mi < 4; mi++)
#pragma unroll
      for (int ni = 0; ni < 4; ni++)
        acc[mi][ni] = __builtin_amdgcn_mfma_f32_16x16x32_bf16(af[mi], bfr[ni], acc[mi][ni], 0, 0, 0);
  }
  // C/D layout (m89): col = lane&15, row = quad*4 + reg
  if (MODE == 0) {
#pragma unroll
    for (int mi = 0; mi < 4; mi++) {
      int row0 = tile_m + wm + mi * 16 + quad * 4;
#pragma unroll
      for (int ni = 0; ni < 4; ni++) {
        int col = tile_n + wn + ni * 16 + c16;
#pragma unroll
        for (int r = 0; r < 4; r++)
          CoutF[(size_t)(row0 + r) * N + col] = acc[mi][ni][r];
      }
    }
  } else {
#pragma unroll
    for (int ni = 0; ni < 4; ni++) {
      int colg = tile_n + wn + ni * 16 + c16;
      int seg = colg >> 10;  // 0=q 1=k 2=v
      int cc = colg & 1023;
      int h = cc >> 6, d = cc & 63, j = d >> 1;
#pragma unroll
      for (int mi = 0; mi < 4; mi++) {
        int row0 = tile_m + wm + mi * 16 + quad * 4;
#pragma unroll
        for (int r = 0; r < 4; r++) {
          int rowg = row0 + r;
          int b = rowg >> 11, t = rowg & 2047;
          float val = acc[mi][ni][r];
          float partner = __shfl_xor(val, 1, 64);
          size_t bh = (size_t)(b * NH + h);
          if (seg == 2) {
            Vt[(bh * HD + d) * T_SEQ + t] = __float2bfloat16(val);
          } else {
            float2 sc = tab[t * 32 + j];
            float outv = ((d & 1) == 0) ? (val * sc.x - partner * sc.y)
                                        : (val * sc.x + partner * sc.y);
            bf16* dst = (seg == 0) ? Qr : Kr;
            dst[(bh * T_SEQ + t) * HD + d] = __float2bfloat16(outv);
          }
        }
      }
    }
  }
}

// ---------------- flash attention (causal), S^T, heavy-first, double-buffered LDS ----------
__global__ __launch_bounds__(256) void attn_kernel(const bf16* __restrict__ Qr,
                                                   const bf16* __restrict__ Kr,
                                                   const bf16* __restrict__ Vt,
                                                   bf16* __restrict__ Y) {
  constexpr int DPAD = 68;
  __shared__ __align__(16) bf16 Ks[2][64 * DPAD];  // [buf][k_local][d]
  __shared__ __align__(16) bf16 Vs[2][64 * DPAD];  // [buf][d][k_local]
  __shared__ __align__(16) bf16 Ps[4][16 * DPAD];  // per-wave [q_local(16)][k(64)]
  const int qtile = 31 - (blockIdx.x >> 5), bh = blockIdx.x & 31;
  const int b = bh >> 4, h = bh & 15;
  const int tid = threadIdx.x, lane = tid & 63, wave = tid >> 6;
  const int quad = lane >> 4, c16 = lane & 15;
  const size_t hoff = (size_t)bh * T_SEQ * HD;
  const int row0 = tid >> 3, cp = tid & 7;  // staging: rows row0 / row0+32
  const int qbase = qtile * 64;
  const int qg = qbase + wave * 16 + c16;  // this lane's q row (softmax state owner)
  bf16x8 qf0 = *(const bf16x8*)&Qr[hoff + (size_t)qg * HD + quad * 8];
  bf16x8 qf1 = *(const bf16x8*)&Qr[hoff + (size_t)qg * HD + 32 + quad * 8];
  floatx4 o_acc[4] = {};  // o_acc[dt][r]: q=wave*16+quad*4+r, d=dt*16+c16
  float m_run = -1e30f, l_run = 0.f;
  // preload kt=0 K/V into regs, stage into buf 0
  bf16x8 kreg0 = *(const bf16x8*)&Kr[hoff + (size_t)row0 * HD + cp * 8];
  bf16x8 kreg1 = *(const bf16x8*)&Kr[hoff + (size_t)(row0 + 32) * HD + cp * 8];
  bf16x8 vreg0 = *(const bf16x8*)&Vt[hoff + (size_t)row0 * T_SEQ + cp * 8];
  bf16x8 vreg1 = *(const bf16x8*)&Vt[hoff + (size_t)(row0 + 32) * T_SEQ + cp * 8];
  *(bf16x8*)&Ks[0][row0 * DPAD + cp * 8] = kreg0;
  *(bf16x8*)&Ks[0][(row0 + 32) * DPAD + cp * 8] = kreg1;
  *(bf16x8*)&Vs[0][row0 * DPAD + cp * 8] = vreg0;
  *(bf16x8*)&Vs[0][(row0 + 32) * DPAD + cp * 8] = vreg1;
  __syncthreads();
  for (int kt = 0; kt <= qtile; ++kt) {
    const int kbase = kt * 64;
    const int cur = kt & 1;
    // issue next tile's global loads now; drained at the LDS write below (compute hides latency)
    if (kt < qtile) {
      const int nb = kbase + 64;
      kreg0 = *(const bf16x8*)&Kr[hoff + (size_t)(nb + row0) * HD + cp * 8];
      kreg1 = *(const bf16x8*)&Kr[hoff + (size_t)(nb + row0 + 32) * HD + cp * 8];
      vreg0 = *(const bf16x8*)&Vt[hoff + (size_t)row0 * T_SEQ + nb + cp * 8];
      vreg1 = *(const bf16x8*)&Vt[hoff + (size_t)(row0 + 32) * T_SEQ + nb + cp * 8];
    }
    // S^T[k_local][q] = K . Q^T : A-frag = K rows, B-frag = Q rows
    floatx4 s[4];
#pragma unroll
    for (int nt = 0; nt < 4; nt++) {
      bf16x8 kf0 = *(const bf16x8*)&Ks[cur][(nt * 16 + c16) * DPAD + quad * 8];
      bf16x8 kf1 = *(const bf16x8*)&Ks[cur][(nt * 16 + c16) * DPAD + 32 + quad * 8];
      floatx4 z = {0.f, 0.f, 0.f, 0.f};
      z = __builtin_amdgcn_mfma_f32_16x16x32_bf16(kf0, qf0, z, 0, 0, 0);
      z = __builtin_amdgcn_mfma_f32_16x16x32_bf16(kf1, qf1, z, 0, 0, 0);
      s[nt] = z;  // row = k_local = nt*16+quad*4+r, col = q = c16
    }
    const bool diag = (kt == qtile);
    float mloc = -1e30f;
#pragma unroll
    for (int nt = 0; nt < 4; nt++)
#pragma unroll
      for (int r = 0; r < 4; r++) {
        float v = s[nt][r] * 0.125f;
        if (diag) {
          int kg = kbase + nt * 16 + quad * 4 + r;
          v = (kg <= qg) ? v : -1e30f;
        }
        s[nt][r] = v;
        mloc = fmaxf(mloc, v);
      }
    mloc = fmaxf(mloc, __shfl_xor(mloc, 16, 64));
    mloc = fmaxf(mloc, __shfl_xor(mloc, 32, 64));
    float mn = fmaxf(m_run, mloc);
    float alpha = __expf(m_run - mn);
    m_run = mn;
    float lloc = 0.f;
    union { bf16 h[4]; s16x4 sv; } ph[4];
#pragma unroll
    for (int nt = 0; nt < 4; nt++)
#pragma unroll
      for (int r = 0; r < 4; r++) {
        float pp = __expf(s[nt][r] - mn);
        lloc += pp;
        ph[nt].h[r] = __float2bfloat16(pp);
      }
    lloc += __shfl_xor(lloc, 16, 64);
    lloc += __shfl_xor(lloc, 32, 64);
    l_run = l_run * alpha + lloc;
    // P[q=c16][k=nt*16+quad*4+r] -> Ps[wave][q][k] (per-wave region, no barrier needed)
#pragma unroll
    for (int nt = 0; nt < 4; nt++)
      *(s16x4*)&Ps[wave][c16 * DPAD + nt * 16 + quad * 4] = ph[nt].sv;
    // broadcast alpha from state-lane (c16 = quad*4+r) to o_acc rows
    float a_bc[4];
#pragma unroll
    for (int r = 0; r < 4; r++) a_bc[r] = __shfl(alpha, quad * 4 + r, 16);
#pragma unroll
    for (int dt = 0; dt < 4; dt++)
#pragma unroll
      for (int r = 0; r < 4; r++) o_acc[dt][r] *= a_bc[r];
    // O += P.V  (A=P from Ps, B=V^T rows from Vs[cur])
    bf16x8 pf0 = *(const bf16x8*)&Ps[wave][c16 * DPAD + quad * 8];
    bf16x8 pf1 = *(const bf16x8*)&Ps[wave][c16 * DPAD + 32 + quad * 8];
#pragma unroll
    for (int dt = 0; dt < 4; dt++) {
      bf16x8 vf0 = *(const bf16x8*)&Vs[cur][(dt * 16 + c16) * DPAD + quad * 8];
      bf16x8 vf1 = *(const bf16x8*)&Vs[cur][(dt * 16 + c16) * DPAD + 32 + quad * 8];
      o_acc[dt] = __builtin_amdgcn_mfma_f32_16x16x32_bf16(pf0, vf0, o_acc[dt], 0, 0, 0);
      o_acc[dt] = __builtin_amdgcn_mfma_f32_16x16x32_bf16(pf1, vf1, o_acc[dt], 0, 0, 0);
    }
    // stage next tile into the other buffer (its readers finished before last barrier)
    if (kt < qtile) {
      const int nxt = cur ^ 1;
      *(bf16x8*)&Ks[nxt][row0 * DPAD + cp * 8] = kreg0;
      *(bf16x8*)&Ks[nxt][(row0 + 32) * DPAD + cp * 8] = kreg1;
      *(bf16x8*)&Vs[nxt][row0 * DPAD + cp * 8] = vreg0;
      *(bf16x8*)&Vs[nxt][(row0 + 32) * DPAD + cp * 8] = vreg1;
    }
    __syncthreads();  // single barrier per iter
  }
  // epilogue: broadcast 1/l to rows, store O[q][d]
  float linv = 1.0f / l_run;
  float l_bc[4];
#pragma unroll
  for (int r = 0; r < 4; r++) l_bc[r] = __shfl(linv, quad * 4 + r, 16);
#pragma unroll
  for (int dt = 0; dt < 4; dt++)
#pragma unroll
    for (int r = 0; r < 4; r++) {
      int t = qbase + wave * 16 + quad * 4 + r;
      Y[((size_t)(b * T_SEQ + t)) * CDIM + h * HD + dt * 16 + c16] =
          __float2bfloat16(o_acc[dt][r] * l_bc[r]);
    }
}

// ---------------- launch ----------------
extern "C" void kernel_launch(void* const* d_in, const int* in_sizes, int n_in,
                              void* d_out, int out_size, void* d_ws, size_t ws_size,
                              hipStream_t stream) {
  const float* x    = (const float*)d_in[0];   // [B,T,C] fp32
  const float* Wqkv = (const float*)d_in[2];   // [C,3C] fp32
  const float* Wo   = (const float*)d_in[3];   // [C,C] fp32
  float* out = (float*)d_out;                  // [B,T,C] fp32

  bf16* ws    = (bf16*)d_ws;
  bf16* Xb    = ws;                          // [4096][1024]
  bf16* WqkvT = Xb + 4194304;                // [3072][1024]
  bf16* WoT   = WqkvT + 3072 * 1024;         // [1024][1024]
  bf16* Qr    = WoT + 1024 * 1024;           // [B,H,T,D]
  bf16* Kr    = Qr + 4194304;                // [B,H,T,D]
  bf16* Vt    = Kr + 4194304;                // [B,H,D,T]
  bf16* Y     = Vt + 4194304;                // [B,T,C]
  float2* tab = (float2*)(Y + 4194304);      // [T][32]

  prep_kernel<<<dim3(8448), 256, 0, stream>>>(x, Wqkv, Wo, Xb, WqkvT, WoT, tab);
  gemm_bt<1><<<dim3(3072 / 128, 4096 / 128), 256, 0, stream>>>(
      Xb, WqkvT, nullptr, tab, Qr, Kr, Vt, 4096, 3072, 1024);
  attn_kernel<<<dim3(1024), 256, 0, stream>>>(Qr, Kr, Vt, Y);
  gemm_bt<0><<<dim3(1024 / 128, 4096 / 128), 256, 0, stream>>>(
      Y, WoT, out, nullptr, nullptr, nullptr, nullptr, 4096, 1024, 1024);
}